// Round 5
// baseline (617.136 us; speedup 1.0000x reference)
//
#include <hip/hip_runtime.h>

#define NEG_INF_F (-1.0e9f)

typedef short bf16x8 __attribute__((ext_vector_type(8)));
typedef float f32x4 __attribute__((ext_vector_type(4)));

__device__ inline unsigned short bf_rne(float f) {
    unsigned u = __builtin_bit_cast(unsigned, f);
    u = (u + 0x7fffu + ((u >> 16) & 1u)) >> 16;
    return (unsigned short)u;
}
__device__ inline float bf_to_f32(unsigned short h) {
    unsigned u = ((unsigned)h) << 16;
    return __builtin_bit_cast(float, u);
}

// async global->LDS, 16B per lane; LDS dest = wave-uniform base + lane*16
__device__ inline void gload16(const unsigned short* g, unsigned short* l) {
    __builtin_amdgcn_global_load_lds(
        (const __attribute__((address_space(1))) unsigned int*)g,
        (__attribute__((address_space(3))) unsigned int*)l, 16, 0, 0);
}

// Swizzled fragment reads. frag32: [R][32]-bf16 tile, chunk ^((r>>1)&3).
__device__ inline bf16x8 frag32(const unsigned short* t, int r, int ch) {
    return *reinterpret_cast<const bf16x8*>(&t[r * 32 + (ch ^ ((r >> 1) & 3)) * 8]);
}
// frag64: [R][64]-bf16 tile, chunk ^(r&7).
__device__ inline bf16x8 frag64(const unsigned short* t, int r, int ch) {
    return *reinterpret_cast<const bf16x8*>(&t[r * 64 + (ch ^ (r & 7)) * 8]);
}

// ---- stage one K-tile into a 48KB buffer: exactly 6 gload16 per wave ----
// TERMS=3: Ah[256x32]@0, Al@8192, Bh[128x32]@16384, Bl@20480  (BK=32)
// TERMS=1: A [256x64]@0, B [128x64]@16384                      (BK=64)
template <int TERMS>
__device__ inline void stage_ktile(
    const unsigned short* __restrict__ Ah0, const unsigned short* __restrict__ Al0, int lda,
    const unsigned short* __restrict__ Bh0, const unsigned short* __restrict__ Bl0, int ldb,
    int k0, unsigned short* buf, int w, int lane)
{
    if constexpr (TERMS == 3) {
#pragma unroll
        for (int p = 0; p < 2; ++p) {
            const int idx = p * 512 + w * 64 + lane;
            const int r = idx >> 2;
            const int cl = (idx & 3) ^ ((r >> 1) & 3);
            gload16(Ah0 + (long long)r * lda + k0 + cl * 8, buf + (p * 512 + w * 64) * 8);
        }
#pragma unroll
        for (int p = 0; p < 2; ++p) {
            const int idx = p * 512 + w * 64 + lane;
            const int r = idx >> 2;
            const int cl = (idx & 3) ^ ((r >> 1) & 3);
            gload16(Al0 + (long long)r * lda + k0 + cl * 8, buf + 8192 + (p * 512 + w * 64) * 8);
        }
        {
            const int idx = w * 64 + lane;
            const int r = idx >> 2;
            const int cl = (idx & 3) ^ ((r >> 1) & 3);
            gload16(Bh0 + (long long)r * ldb + k0 + cl * 8, buf + 16384 + (w * 64) * 8);
            gload16(Bl0 + (long long)r * ldb + k0 + cl * 8, buf + 20480 + (w * 64) * 8);
        }
    } else {
#pragma unroll
        for (int p = 0; p < 4; ++p) {
            const int idx = p * 512 + w * 64 + lane;
            const int r = idx >> 3;
            const int cl = (idx & 7) ^ (r & 7);
            gload16(Ah0 + (long long)r * lda + k0 + cl * 8, buf + (p * 512 + w * 64) * 8);
        }
#pragma unroll
        for (int p = 0; p < 2; ++p) {
            const int idx = p * 512 + w * 64 + lane;
            const int r = idx >> 3;
            const int cl = (idx & 7) ^ (r & 7);
            gload16(Bh0 + (long long)r * ldb + k0 + cl * 8, buf + 16384 + (p * 512 + w * 64) * 8);
        }
    }
}

// ---------------- 256x128 8-wave TRIPLE-buffered GEMM, counted vmcnt ----------------
// C = A * B^T. TERMS: 3 = split hi/lo (Ah*Bh+Al*Bh+Ah*Bl); 1 = hi only.
// OMODE: 0 = f32 C (+ optional NEG_INF*mask[col]); 1 = split bf16 (Ch,Cl);
//        3 = bf16 transposed V^T store Ch[b2][col][s].
// Waves: wr=w>>2 (128-row half), wc=w&3 (32-col slice). acc = 8x2 16x16 frags.
template <int TERMS, int OMODE>
__global__ __launch_bounds__(512, 2) void mfma_gemm256(
    const unsigned short* __restrict__ Ah_g, const unsigned short* __restrict__ Al_g,
    long long strideA, int lda,
    const unsigned short* __restrict__ Bh_g, const unsigned short* __restrict__ Bl_g,
    long long strideB, int ldb,
    float* __restrict__ Cf, unsigned short* __restrict__ Ch, unsigned short* __restrict__ Cl,
    long long strideC, int ldc, int K,
    const int* __restrict__ mask, long long strideMask)
{
    constexpr int KT = (TERMS == 3) ? 32 : 64;
    constexpr int BUF = 24576;  // ushorts = 48KB
    const int b = blockIdx.z;
    const int tid = threadIdx.x;
    const int w = tid >> 6, lane = tid & 63;
    const int wr = w >> 2, wc = w & 3;
    const int lr = lane & 15, lg = lane >> 4;
    const int rowBase = blockIdx.x * 256;
    const int colBase = blockIdx.y * 128;

    __shared__ unsigned short smem[73728];  // 144KB = 3 x 48KB

    const unsigned short* Ah0 = Ah_g + (long long)b * strideA + (long long)rowBase * lda;
    const unsigned short* Bh0 = Bh_g + (long long)b * strideB + (long long)colBase * ldb;
    const unsigned short* Al0 = (TERMS == 3)
        ? Al_g + (long long)b * strideA + (long long)rowBase * lda : nullptr;
    const unsigned short* Bl0 = (TERMS == 3)
        ? Bl_g + (long long)b * strideB + (long long)colBase * ldb : nullptr;

    f32x4 acc[8][2] = {};
    const int NT = K / KT;

    // prologue: tiles 0 and 1 in flight; wait tile 0 (6 younger stay in flight)
    stage_ktile<TERMS>(Ah0, Al0, lda, Bh0, Bl0, ldb, 0, smem, w, lane);
    stage_ktile<TERMS>(Ah0, Al0, lda, Bh0, Bl0, ldb, KT, smem + BUF, w, lane);
    asm volatile("s_waitcnt vmcnt(6)" ::: "memory");
    __builtin_amdgcn_s_barrier();

    for (int t = 0; t < NT; ++t) {
        const unsigned short* cbuf = smem + (t % 3) * BUF;
        if (t + 2 < NT)
            stage_ktile<TERMS>(Ah0, Al0, lda, Bh0, Bl0, ldb, (t + 2) * KT,
                               smem + ((t + 2) % 3) * BUF, w, lane);

        if constexpr (TERMS == 3) {
            const unsigned short* tAh = cbuf;
            const unsigned short* tAl = cbuf + 8192;
            const unsigned short* tBh = cbuf + 16384;
            const unsigned short* tBl = cbuf + 20480;
            bf16x8 bh[2], bl[2];
#pragma unroll
            for (int j = 0; j < 2; ++j) {
                bh[j] = frag32(tBh, wc * 32 + j * 16 + lr, lg);
                bl[j] = frag32(tBl, wc * 32 + j * 16 + lr, lg);
            }
#pragma unroll
            for (int f = 0; f < 8; ++f) {
                const int r = wr * 128 + f * 16 + lr;
                const bf16x8 ah = frag32(tAh, r, lg);
                const bf16x8 al = frag32(tAl, r, lg);
#pragma unroll
                for (int j = 0; j < 2; ++j) {
                    f32x4 a = acc[f][j];
                    a = __builtin_amdgcn_mfma_f32_16x16x32_bf16(ah, bh[j], a, 0, 0, 0);
                    a = __builtin_amdgcn_mfma_f32_16x16x32_bf16(al, bh[j], a, 0, 0, 0);
                    a = __builtin_amdgcn_mfma_f32_16x16x32_bf16(ah, bl[j], a, 0, 0, 0);
                    acc[f][j] = a;
                }
            }
        } else {
            const unsigned short* tA = cbuf;
            const unsigned short* tB = cbuf + 16384;
            bf16x8 bfr[2][2];
#pragma unroll
            for (int j = 0; j < 2; ++j)
#pragma unroll
                for (int ks = 0; ks < 2; ++ks)
                    bfr[j][ks] = frag64(tB, wc * 32 + j * 16 + lr, ks * 4 + lg);
#pragma unroll
            for (int f = 0; f < 8; ++f) {
                const int r = wr * 128 + f * 16 + lr;
                const bf16x8 a0 = frag64(tA, r, lg);
                const bf16x8 a1 = frag64(tA, r, 4 + lg);
#pragma unroll
                for (int j = 0; j < 2; ++j) {
                    f32x4 a = acc[f][j];
                    a = __builtin_amdgcn_mfma_f32_16x16x32_bf16(a0, bfr[j][0], a, 0, 0, 0);
                    a = __builtin_amdgcn_mfma_f32_16x16x32_bf16(a1, bfr[j][1], a, 0, 0, 0);
                    acc[f][j] = a;
                }
            }
        }

        // counted wait: tile t+1 done; tile t+2's 6 loads stay in flight
        if (t + 2 < NT) asm volatile("s_waitcnt vmcnt(6)" ::: "memory");
        else            asm volatile("s_waitcnt vmcnt(0)" ::: "memory");
        __builtin_amdgcn_s_barrier();
    }

    // ---- epilogue: per-wave private LDS bounce (8KB), 4 rounds of 32x32 ----
    float* stg = reinterpret_cast<float*>(smem) + w * 2048;
    const int colg0 = colBase + wc * 32;
#pragma unroll
    for (int rnd = 0; rnd < 4; ++rnd) {
        const int rowg0 = rowBase + wr * 128 + rnd * 32;
#pragma unroll
        for (int ii = 0; ii < 2; ++ii)
#pragma unroll
            for (int j = 0; j < 2; ++j)
#pragma unroll
                for (int r2 = 0; r2 < 4; ++r2)
                    stg[(ii * 16 + lg * 4 + r2) * 32 + j * 16 + lr] = acc[rnd * 2 + ii][j][r2];
        __syncthreads();

        if constexpr (OMODE == 0) {
#pragma unroll
            for (int t = 0; t < 4; ++t) {
                const int idx = t * 256 + lane * 4;
                const int r = idx >> 5, c = idx & 31;
                float4 v = *reinterpret_cast<const float4*>(&stg[idx]);
                const int colg = colg0 + c;
                if (mask != nullptr) {
                    const int4 mv = *reinterpret_cast<const int4*>(
                        &mask[(long long)b * strideMask + colg]);
                    v.x += NEG_INF_F * (float)mv.x;
                    v.y += NEG_INF_F * (float)mv.y;
                    v.z += NEG_INF_F * (float)mv.z;
                    v.w += NEG_INF_F * (float)mv.w;
                }
                *reinterpret_cast<float4*>(
                    &Cf[(long long)b * strideC + (long long)(rowg0 + r) * ldc + colg]) = v;
            }
        } else if constexpr (OMODE == 1) {
#pragma unroll
            for (int t = 0; t < 4; ++t) {
                const int idx = t * 256 + lane * 4;
                const int r = idx >> 5, c = idx & 31;
                const float4 v = *reinterpret_cast<const float4*>(&stg[idx]);
                ushort4 h, l;
                h.x = bf_rne(v.x); l.x = bf_rne(v.x - bf_to_f32(h.x));
                h.y = bf_rne(v.y); l.y = bf_rne(v.y - bf_to_f32(h.y));
                h.z = bf_rne(v.z); l.z = bf_rne(v.z - bf_to_f32(h.z));
                h.w = bf_rne(v.w); l.w = bf_rne(v.w - bf_to_f32(h.w));
                const long long cidx = (long long)(rowg0 + r) * ldc + colg0 + c;
                *reinterpret_cast<ushort4*>(&Ch[cidx]) = h;
                *reinterpret_cast<ushort4*>(&Cl[cidx]) = l;
            }
        } else {  // OMODE 3: V^T store  Ch[b2][col][s]
            const int c = lane & 31, h = lane >> 5;
            const int b2 = rowg0 >> 11;
            const int s0 = (rowg0 & 2047) + h * 16;
            alignas(16) unsigned short u[16];
#pragma unroll
            for (int rr = 0; rr < 16; ++rr) u[rr] = bf_rne(stg[(h * 16 + rr) * 32 + c]);
            unsigned short* vp = Ch + (long long)b2 * (1024LL * 2048)
                               + (long long)(colg0 + c) * 2048 + s0;
            *reinterpret_cast<uint4*>(vp)     = *reinterpret_cast<const uint4*>(&u[0]);
            *reinterpret_cast<uint4*>(vp + 8) = *reinterpret_cast<const uint4*>(&u[8]);
        }
        __syncthreads();
    }
}

// ---------------- helpers ----------------
__global__ __launch_bounds__(256) void split2_kernel(
    const float* __restrict__ in, unsigned short* __restrict__ hi,
    unsigned short* __restrict__ lo, long long n)
{
    for (long long i = ((long long)blockIdx.x * 256 + threadIdx.x) * 4; i < n;
         i += (long long)gridDim.x * 256 * 4) {
        float4 v = *reinterpret_cast<const float4*>(&in[i]);
        ushort4 h, l;
        h.x = bf_rne(v.x); l.x = bf_rne(v.x - bf_to_f32(h.x));
        h.y = bf_rne(v.y); l.y = bf_rne(v.y - bf_to_f32(h.y));
        h.z = bf_rne(v.z); l.z = bf_rne(v.z - bf_to_f32(h.z));
        h.w = bf_rne(v.w); l.w = bf_rne(v.w - bf_to_f32(h.w));
        *reinterpret_cast<ushort4*>(&hi[i]) = h;
        *reinterpret_cast<ushort4*>(&lo[i]) = l;
    }
}

__global__ __launch_bounds__(256) void cvt_kernel(
    const float* __restrict__ in, unsigned short* __restrict__ out, long long n)
{
    for (long long i = ((long long)blockIdx.x * 256 + threadIdx.x) * 4; i < n;
         i += (long long)gridDim.x * 256 * 4) {
        float4 v = *reinterpret_cast<const float4*>(&in[i]);
        ushort4 h;
        h.x = bf_rne(v.x); h.y = bf_rne(v.y); h.z = bf_rne(v.z); h.w = bf_rne(v.w);
        *reinterpret_cast<ushort4*>(&out[i]) = h;
    }
}

__global__ __launch_bounds__(256) void softmax_kernel(
    float* __restrict__ s, unsigned short* __restrict__ p)
{
    const long long row = blockIdx.x;
    float* sp = s + row * 2048;
    const int tid = threadIdx.x;

    float v[8];
    *reinterpret_cast<float4*>(&v[0]) = *reinterpret_cast<const float4*>(&sp[tid * 8]);
    *reinterpret_cast<float4*>(&v[4]) = *reinterpret_cast<const float4*>(&sp[tid * 8 + 4]);

    float m = v[0];
#pragma unroll
    for (int i = 1; i < 8; ++i) m = fmaxf(m, v[i]);
#pragma unroll
    for (int off = 1; off < 64; off <<= 1) m = fmaxf(m, __shfl_xor(m, off));

    __shared__ float redm[4];
    __shared__ float reds[4];
    if ((tid & 63) == 0) redm[tid >> 6] = m;
    __syncthreads();
    m = fmaxf(fmaxf(redm[0], redm[1]), fmaxf(redm[2], redm[3]));

    float sum = 0.f;
#pragma unroll
    for (int i = 0; i < 8; ++i) {
        v[i] = __expf(v[i] - m);
        sum += v[i];
    }
#pragma unroll
    for (int off = 1; off < 64; off <<= 1) sum += __shfl_xor(sum, off);
    if ((tid & 63) == 0) reds[tid >> 6] = sum;
    __syncthreads();
    sum = reds[0] + reds[1] + reds[2] + reds[3];

    const float inv = 1.0f / sum;
#pragma unroll
    for (int i = 0; i < 8; ++i) v[i] *= inv;

    *reinterpret_cast<float4*>(&sp[tid * 8])     = *reinterpret_cast<const float4*>(&v[0]);
    *reinterpret_cast<float4*>(&sp[tid * 8 + 4]) = *reinterpret_cast<const float4*>(&v[4]);

    ushort4 o0, o1;
    o0.x = bf_rne(v[0]); o0.y = bf_rne(v[1]); o0.z = bf_rne(v[2]); o0.w = bf_rne(v[3]);
    o1.x = bf_rne(v[4]); o1.y = bf_rne(v[5]); o1.z = bf_rne(v[6]); o1.w = bf_rne(v[7]);
    *reinterpret_cast<ushort4*>(&p[row * 2048 + tid * 8])     = o0;
    *reinterpret_cast<ushort4*>(&p[row * 2048 + tid * 8 + 4]) = o1;
}

extern "C" void kernel_launch(void* const* d_in, const int* in_sizes, int n_in,
                              void* d_out, int out_size, void* d_ws, size_t ws_size,
                              hipStream_t stream)
{
    (void)in_sizes; (void)n_in; (void)out_size; (void)ws_size;

    const int S = 2048, D = 1024;
    const long long BS  = 8LL * S;
    const long long SD  = (long long)S * D;
    const long long SS  = (long long)S * S;
    const long long BSD = BS * D;
    const long long DD  = (long long)D * D;

    const float* x    = (const float*)d_in[0];
    const int*   mask = (const int*)d_in[1];
    const float* wq   = (const float*)d_in[2];
    const float* wk   = (const float*)d_in[3];
    const float* wv   = (const float*)d_in[4];

    float* out = (float*)d_out;           // [BS, D] f32 (final)
    float* s   = out + BSD;               // [B, S, S] f32 (final)

    // ws: Qh | Ql | Kh | Kl  (bf16, each BSD elems)
    unsigned short* Qh = (unsigned short*)d_ws;
    unsigned short* Ql = Qh + BSD;
    unsigned short* Kh = Ql + BSD;
    unsigned short* Kl = Kh + BSD;

    // x split lives in d_out's out-region until PV overwrites it
    unsigned short* xh = (unsigned short*)out;
    unsigned short* xl = xh + BSD;
    // wq/wk splits live in d_out's s-region until scores overwrites it
    unsigned short* wqh = (unsigned short*)s;
    unsigned short* wql = wqh + DD;
    unsigned short* wkh = wql + DD;
    unsigned short* wkl = wkh + DD;
    // after scores: p reuses Qh+Ql, V^T reuses Kh, wv-bf16 reuses Kl
    unsigned short* p   = Qh;
    unsigned short* Vt  = Kh;
    unsigned short* wvh = Kl;

    dim3 blk256(256), blk512(512);

    split2_kernel<<<dim3(2048), blk256, 0, stream>>>(x, xh, xl, BSD);
    split2_kernel<<<dim3(512), blk256, 0, stream>>>(wq, wqh, wql, DD);
    split2_kernel<<<dim3(512), blk256, 0, stream>>>(wk, wkh, wkl, DD);

    // Q = x @ wq^T, K = x @ wk^T  (3-term, split-bf16 outputs)
    mfma_gemm256<3, 1><<<dim3(64, 8, 1), blk512, 0, stream>>>(
        xh, xl, 0, D, wqh, wql, 0, D, nullptr, Qh, Ql, 0, D, D, nullptr, 0);
    mfma_gemm256<3, 1><<<dim3(64, 8, 1), blk512, 0, stream>>>(
        xh, xl, 0, D, wkh, wkl, 0, D, nullptr, Kh, Kl, 0, D, D, nullptr, 0);

    // scores = Q @ K^T + NEG_INF*mask  (3-term, f32 out)
    mfma_gemm256<3, 0><<<dim3(8, 16, 8), blk512, 0, stream>>>(
        Qh, Ql, SD, D, Kh, Kl, SD, D, s, nullptr, nullptr, SS, S, D, mask, S);

    // softmax in place + bf16 p for PV
    softmax_kernel<<<dim3(16384), blk256, 0, stream>>>(s, p);

    // wv -> bf16, then V^T = (x @ wv^T)^T directly (1-term, transposed store)
    cvt_kernel<<<dim3(512), blk256, 0, stream>>>(wv, wvh, DD);
    mfma_gemm256<1, 3><<<dim3(64, 8, 1), blk512, 0, stream>>>(
        xh, nullptr, 0, D, wvh, nullptr, 0, D, nullptr, Vt, nullptr, 0, 0, D, nullptr, 0);

    // out = p @ V = p @ (V^T)^T  (1-term BK=64, NT form, f32 out)
    mfma_gemm256<1, 0><<<dim3(8, 8, 8), blk512, 0, stream>>>(
        p, nullptr, SS, S, Vt, nullptr, SD, S, out, nullptr, nullptr, SD, D, S, nullptr, 0);
}

// Round 6
// 521.090 us; speedup vs baseline: 1.1843x; 1.1843x over previous
//
#include <hip/hip_runtime.h>

#define NEG_INF_F (-1.0e9f)

typedef short bf16x8 __attribute__((ext_vector_type(8)));
typedef float f32x4 __attribute__((ext_vector_type(4)));

__device__ inline unsigned short bf_rne(float f) {
    unsigned u = __builtin_bit_cast(unsigned, f);
    u = (u + 0x7fffu + ((u >> 16) & 1u)) >> 16;
    return (unsigned short)u;
}
__device__ inline float bf_to_f32(unsigned short h) {
    unsigned u = ((unsigned)h) << 16;
    return __builtin_bit_cast(float, u);
}

// async global->LDS, 16B per lane; LDS dest = wave-uniform base + lane*16
__device__ inline void gload16(const unsigned short* g, unsigned short* l) {
    __builtin_amdgcn_global_load_lds(
        (const __attribute__((address_space(1))) unsigned int*)g,
        (__attribute__((address_space(3))) unsigned int*)l, 16, 0, 0);
}

// ---------------- 256x256 8-wave double-buffered GEMM (round-4 structure) ----
// C = A * B^T. TERMS: 3 = split hi/lo (Ah*Bh+Al*Bh+Ah*Bl), BK=32;
//              1 = hi only, BK=64.
// OMODE: 0 = f32 C (+ optional NEG_INF*mask[col]); 1 = split bf16 (Ch,Cl);
//        3 = bf16 transposed V^T store Ch[b2][col][s].

// TERMS=3 tile [256][32] bf16 (8192 ushorts), chunk swizzle ^((r>>1)&3)
__device__ inline bf16x8 frag32(const unsigned short* t, int r, int ch) {
    return *reinterpret_cast<const bf16x8*>(&t[r * 32 + (ch ^ ((r >> 1) & 3)) * 8]);
}
// TERMS=1 tile [256][64] bf16 (16384 ushorts), chunk swizzle ^(r&7)
__device__ inline bf16x8 frag64(const unsigned short* t, int r, int ch) {
    return *reinterpret_cast<const bf16x8*>(&t[r * 64 + (ch ^ (r & 7)) * 8]);
}

template <int TERMS>
__device__ inline void stage_ktile(
    const unsigned short* __restrict__ Ah0, const unsigned short* __restrict__ Al0, int lda,
    const unsigned short* __restrict__ Bh0, const unsigned short* __restrict__ Bl0, int ldb,
    int k0, unsigned short* buf, int w, int lane)
{
    if constexpr (TERMS == 3) {
#pragma unroll
        for (int c = 0; c < 2; ++c) {
            const int r = c * 128 + w * 16 + (lane >> 2);
            const int co = ((lane & 3) ^ ((r >> 1) & 3)) * 8;
            const int lb = (c * 128 + w * 16) * 32;
            gload16(Ah0 + (long long)r * lda + k0 + co, buf + lb);
            gload16(Al0 + (long long)r * lda + k0 + co, buf + 8192 + lb);
            gload16(Bh0 + (long long)r * ldb + k0 + co, buf + 16384 + lb);
            gload16(Bl0 + (long long)r * ldb + k0 + co, buf + 24576 + lb);
        }
    } else {
#pragma unroll
        for (int c = 0; c < 4; ++c) {
            const int r = c * 64 + w * 8 + (lane >> 3);
            const int co = ((lane & 7) ^ (r & 7)) * 8;
            const int lb = (c * 64 + w * 8) * 64;
            gload16(Ah0 + (long long)r * lda + k0 + co, buf + lb);
            gload16(Bh0 + (long long)r * ldb + k0 + co, buf + 16384 + lb);
        }
    }
}

template <int TERMS, int OMODE>
__global__ __launch_bounds__(512, 2) void mfma_gemm256(
    const unsigned short* __restrict__ Ah_g, const unsigned short* __restrict__ Al_g,
    long long strideA, int lda,
    const unsigned short* __restrict__ Bh_g, const unsigned short* __restrict__ Bl_g,
    long long strideB, int ldb,
    float* __restrict__ Cf, unsigned short* __restrict__ Ch, unsigned short* __restrict__ Cl,
    long long strideC, int ldc, int K,
    const int* __restrict__ mask, long long strideMask)
{
    constexpr int KT = (TERMS == 3) ? 32 : 64;
    const int b = blockIdx.z;
    const int tid = threadIdx.x;
    const int w = tid >> 6, lane = tid & 63;
    const int wr = w >> 2, wc = w & 3;
    const int lr = lane & 15, lg = lane >> 4;
    const int rowBase = blockIdx.x * 256;
    const int colBase = blockIdx.y * 256;

    __shared__ unsigned short smem[65536];  // 128 KB: 2 x 64KB buffers

    const unsigned short* Ah0 = Ah_g + (long long)b * strideA + (long long)rowBase * lda;
    const unsigned short* Bh0 = Bh_g + (long long)b * strideB + (long long)colBase * ldb;
    const unsigned short* Al0 = (TERMS == 3)
        ? Al_g + (long long)b * strideA + (long long)rowBase * lda : nullptr;
    const unsigned short* Bl0 = (TERMS == 3)
        ? Bl_g + (long long)b * strideB + (long long)colBase * ldb : nullptr;

    f32x4 acc[8][4] = {};
    const int NT = K / KT;

    stage_ktile<TERMS>(Ah0, Al0, lda, Bh0, Bl0, ldb, 0, smem, w, lane);
    __syncthreads();

    for (int kt = 0; kt < NT; ++kt) {
        unsigned short* cbuf = smem + (kt & 1) * 32768;
        if (kt + 1 < NT)
            stage_ktile<TERMS>(Ah0, Al0, lda, Bh0, Bl0, ldb, (kt + 1) * KT,
                               smem + ((kt + 1) & 1) * 32768, w, lane);

        if constexpr (TERMS == 3) {
            const unsigned short* tAh = cbuf;
            const unsigned short* tAl = cbuf + 8192;
            const unsigned short* tBh = cbuf + 16384;
            const unsigned short* tBl = cbuf + 24576;
            bf16x8 bh[4], bl[4];
#pragma unroll
            for (int j = 0; j < 4; ++j) {
                const int r = wc * 64 + j * 16 + lr;
                bh[j] = frag32(tBh, r, lg);
                bl[j] = frag32(tBl, r, lg);
            }
#pragma unroll
            for (int ih = 0; ih < 2; ++ih) {
                bf16x8 ah[4], al[4];
#pragma unroll
                for (int f = 0; f < 4; ++f) {
                    const int r = wr * 128 + ih * 64 + f * 16 + lr;
                    ah[f] = frag32(tAh, r, lg);
                    al[f] = frag32(tAl, r, lg);
                }
#pragma unroll
                for (int f = 0; f < 4; ++f)
#pragma unroll
                    for (int j = 0; j < 4; ++j) {
                        f32x4 a = acc[ih * 4 + f][j];
                        a = __builtin_amdgcn_mfma_f32_16x16x32_bf16(ah[f], bh[j], a, 0, 0, 0);
                        a = __builtin_amdgcn_mfma_f32_16x16x32_bf16(al[f], bh[j], a, 0, 0, 0);
                        a = __builtin_amdgcn_mfma_f32_16x16x32_bf16(ah[f], bl[j], a, 0, 0, 0);
                        acc[ih * 4 + f][j] = a;
                    }
            }
        } else {
            const unsigned short* tA = cbuf;
            const unsigned short* tB = cbuf + 16384;
            bf16x8 bh[8];
#pragma unroll
            for (int j = 0; j < 4; ++j)
#pragma unroll
                for (int ks = 0; ks < 2; ++ks)
                    bh[j * 2 + ks] = frag64(tB, wc * 64 + j * 16 + lr, ks * 4 + lg);
#pragma unroll
            for (int ih = 0; ih < 2; ++ih) {
                bf16x8 ah[8];
#pragma unroll
                for (int f = 0; f < 4; ++f)
#pragma unroll
                    for (int ks = 0; ks < 2; ++ks)
                        ah[f * 2 + ks] = frag64(tA, wr * 128 + ih * 64 + f * 16 + lr, ks * 4 + lg);
#pragma unroll
                for (int f = 0; f < 4; ++f)
#pragma unroll
                    for (int j = 0; j < 4; ++j) {
                        f32x4 a = acc[ih * 4 + f][j];
                        a = __builtin_amdgcn_mfma_f32_16x16x32_bf16(ah[f * 2 + 0], bh[j * 2 + 0], a, 0, 0, 0);
                        a = __builtin_amdgcn_mfma_f32_16x16x32_bf16(ah[f * 2 + 1], bh[j * 2 + 1], a, 0, 0, 0);
                        acc[ih * 4 + f][j] = a;
                    }
            }
        }
        __syncthreads();
    }

    // ---- epilogue: per-wave LDS bounce (8KB region), 4 rounds of 32x64 ----
    float* stg = reinterpret_cast<float*>(smem) + w * 2048;
    const int colg0 = colBase + wc * 64;
#pragma unroll
    for (int rnd = 0; rnd < 4; ++rnd) {
        const int rowg0 = rowBase + wr * 128 + rnd * 32;
#pragma unroll
        for (int ii = 0; ii < 2; ++ii)
#pragma unroll
            for (int j = 0; j < 4; ++j)
#pragma unroll
                for (int r2 = 0; r2 < 4; ++r2)
                    stg[(ii * 16 + lg * 4 + r2) * 64 + j * 16 + lr] = acc[rnd * 2 + ii][j][r2];
        __syncthreads();

        if constexpr (OMODE == 0) {
#pragma unroll
            for (int t = 0; t < 8; ++t) {
                const int idx = t * 256 + lane * 4;
                const int r = idx >> 6, c = idx & 63;
                float4 v = *reinterpret_cast<const float4*>(&stg[idx]);
                const int colg = colg0 + c;
                if (mask != nullptr) {
                    const int4 mv = *reinterpret_cast<const int4*>(
                        &mask[(long long)b * strideMask + colg]);
                    v.x += NEG_INF_F * (float)mv.x;
                    v.y += NEG_INF_F * (float)mv.y;
                    v.z += NEG_INF_F * (float)mv.z;
                    v.w += NEG_INF_F * (float)mv.w;
                }
                *reinterpret_cast<float4*>(
                    &Cf[(long long)b * strideC + (long long)(rowg0 + r) * ldc + colg]) = v;
            }
        } else if constexpr (OMODE == 1) {
#pragma unroll
            for (int t = 0; t < 8; ++t) {
                const int idx = t * 256 + lane * 4;
                const int r = idx >> 6, c = idx & 63;
                const float4 v = *reinterpret_cast<const float4*>(&stg[idx]);
                ushort4 h, l;
                h.x = bf_rne(v.x); l.x = bf_rne(v.x - bf_to_f32(h.x));
                h.y = bf_rne(v.y); l.y = bf_rne(v.y - bf_to_f32(h.y));
                h.z = bf_rne(v.z); l.z = bf_rne(v.z - bf_to_f32(h.z));
                h.w = bf_rne(v.w); l.w = bf_rne(v.w - bf_to_f32(h.w));
                const long long cidx = (long long)(rowg0 + r) * ldc + colg0 + c;
                *reinterpret_cast<ushort4*>(&Ch[cidx]) = h;
                *reinterpret_cast<ushort4*>(&Cl[cidx]) = l;
            }
        } else {  // OMODE 3: V^T store  Ch[b2][col][s]
            const int b2 = rowg0 >> 11;
            const int s0 = rowg0 & 2047;
            const int colg = colg0 + lane;
            alignas(16) unsigned short u[32];
#pragma unroll
            for (int rr = 0; rr < 32; ++rr) u[rr] = bf_rne(stg[rr * 64 + lane]);
            unsigned short* vp = Ch + (long long)b2 * (1024LL * 2048)
                               + (long long)colg * 2048 + s0;
#pragma unroll
            for (int q = 0; q < 4; ++q)
                *reinterpret_cast<uint4*>(vp + q * 8) =
                    *reinterpret_cast<const uint4*>(&u[q * 8]);
        }
        __syncthreads();
    }
}

// ---------------- helpers ----------------
__global__ __launch_bounds__(256) void split2_kernel(
    const float* __restrict__ in, unsigned short* __restrict__ hi,
    unsigned short* __restrict__ lo, long long n)
{
    for (long long i = ((long long)blockIdx.x * 256 + threadIdx.x) * 4; i < n;
         i += (long long)gridDim.x * 256 * 4) {
        float4 v = *reinterpret_cast<const float4*>(&in[i]);
        ushort4 h, l;
        h.x = bf_rne(v.x); l.x = bf_rne(v.x - bf_to_f32(h.x));
        h.y = bf_rne(v.y); l.y = bf_rne(v.y - bf_to_f32(h.y));
        h.z = bf_rne(v.z); l.z = bf_rne(v.z - bf_to_f32(h.z));
        h.w = bf_rne(v.w); l.w = bf_rne(v.w - bf_to_f32(h.w));
        *reinterpret_cast<ushort4*>(&hi[i]) = h;
        *reinterpret_cast<ushort4*>(&lo[i]) = l;
    }
}

__global__ __launch_bounds__(256) void cvt_kernel(
    const float* __restrict__ in, unsigned short* __restrict__ out, long long n)
{
    for (long long i = ((long long)blockIdx.x * 256 + threadIdx.x) * 4; i < n;
         i += (long long)gridDim.x * 256 * 4) {
        float4 v = *reinterpret_cast<const float4*>(&in[i]);
        ushort4 h;
        h.x = bf_rne(v.x); h.y = bf_rne(v.y); h.z = bf_rne(v.z); h.w = bf_rne(v.w);
        *reinterpret_cast<ushort4*>(&out[i]) = h;
    }
}

__global__ __launch_bounds__(256) void softmax_kernel(
    float* __restrict__ s, unsigned short* __restrict__ p)
{
    const long long row = blockIdx.x;
    float* sp = s + row * 2048;
    const int tid = threadIdx.x;

    float v[8];
    *reinterpret_cast<float4*>(&v[0]) = *reinterpret_cast<const float4*>(&sp[tid * 8]);
    *reinterpret_cast<float4*>(&v[4]) = *reinterpret_cast<const float4*>(&sp[tid * 8 + 4]);

    float m = v[0];
#pragma unroll
    for (int i = 1; i < 8; ++i) m = fmaxf(m, v[i]);
#pragma unroll
    for (int off = 1; off < 64; off <<= 1) m = fmaxf(m, __shfl_xor(m, off));

    __shared__ float redm[4];
    __shared__ float reds[4];
    if ((tid & 63) == 0) redm[tid >> 6] = m;
    __syncthreads();
    m = fmaxf(fmaxf(redm[0], redm[1]), fmaxf(redm[2], redm[3]));

    float sum = 0.f;
#pragma unroll
    for (int i = 0; i < 8; ++i) {
        v[i] = __expf(v[i] - m);
        sum += v[i];
    }
#pragma unroll
    for (int off = 1; off < 64; off <<= 1) sum += __shfl_xor(sum, off);
    if ((tid & 63) == 0) reds[tid >> 6] = sum;
    __syncthreads();
    sum = reds[0] + reds[1] + reds[2] + reds[3];

    const float inv = 1.0f / sum;
#pragma unroll
    for (int i = 0; i < 8; ++i) v[i] *= inv;

    *reinterpret_cast<float4*>(&sp[tid * 8])     = *reinterpret_cast<const float4*>(&v[0]);
    *reinterpret_cast<float4*>(&sp[tid * 8 + 4]) = *reinterpret_cast<const float4*>(&v[4]);

    ushort4 o0, o1;
    o0.x = bf_rne(v[0]); o0.y = bf_rne(v[1]); o0.z = bf_rne(v[2]); o0.w = bf_rne(v[3]);
    o1.x = bf_rne(v[4]); o1.y = bf_rne(v[5]); o1.z = bf_rne(v[6]); o1.w = bf_rne(v[7]);
    *reinterpret_cast<ushort4*>(&p[row * 2048 + tid * 8])     = o0;
    *reinterpret_cast<ushort4*>(&p[row * 2048 + tid * 8 + 4]) = o1;
}

extern "C" void kernel_launch(void* const* d_in, const int* in_sizes, int n_in,
                              void* d_out, int out_size, void* d_ws, size_t ws_size,
                              hipStream_t stream)
{
    (void)in_sizes; (void)n_in; (void)out_size; (void)ws_size;

    const int S = 2048, D = 1024;
    const long long BS  = 8LL * S;          // 16384
    const long long SD  = (long long)S * D;
    const long long SS  = (long long)S * S;
    const long long BSD = BS * D;
    const long long DD  = (long long)D * D;

    const float* x    = (const float*)d_in[0];
    const int*   mask = (const int*)d_in[1];
    const float* wq   = (const float*)d_in[2];
    const float* wk   = (const float*)d_in[3];
    const float* wv   = (const float*)d_in[4];

    float* out = (float*)d_out;             // [BS, D] f32 (final)
    float* s   = out + BSD;                 // [B, S, S] f32 (final)

    // ws: QKh [16384][2048] | QKl [16384][2048]  (bf16): Q = cols 0..1023, K = cols 1024..2047
    unsigned short* QKh = (unsigned short*)d_ws;
    unsigned short* QKl = QKh + BS * 2048;

    // x split lives in d_out's out-region until PV overwrites it
    unsigned short* xh = (unsigned short*)out;
    unsigned short* xl = xh + BSD;
    // stacked weight splits [wq;wk] live in d_out's s-region until scores overwrites it
    unsigned short* whh = (unsigned short*)s;      // [2048][1024] hi
    unsigned short* wll = whh + 2 * DD;            // [2048][1024] lo
    // after scores: p reuses QKh; V^T + wv-bf16 reuse QKl
    unsigned short* p   = QKh;                     // [B][S][S] bf16 (67MB)
    unsigned short* Vt  = QKl;                     // [B][D][S] bf16 (33.5MB)
    unsigned short* wvh = QKl + 8LL * 1024 * 2048; // [1024][1024] bf16

    dim3 blk256(256), blk512(512);

    split2_kernel<<<dim3(2048), blk256, 0, stream>>>(x, xh, xl, BSD);
    split2_kernel<<<dim3(512), blk256, 0, stream>>>(wq, whh, wll, DD);
    split2_kernel<<<dim3(512), blk256, 0, stream>>>(wk, whh + DD, wll + DD, DD);

    // Merged Q|K projection: M=16384, N=2048 (cols 0..1023 = Q, 1024..2047 = K)
    mfma_gemm256<3, 1><<<dim3(64, 8, 1), blk512, 0, stream>>>(
        xh, xl, 0, D, whh, wll, 0, D,
        nullptr, QKh, QKl, 0, 2048, D, nullptr, 0);

    // scores = Q @ K^T + NEG_INF*mask  (3-term, f32 out); Q,K are column slices
    mfma_gemm256<3, 0><<<dim3(8, 8, 8), blk512, 0, stream>>>(
        QKh, QKl, (long long)S * 2048, 2048,
        QKh + 1024, QKl + 1024, (long long)S * 2048, 2048,
        s, nullptr, nullptr, SS, S, D, mask, S);

    // softmax in place + bf16 p for PV (p overwrites QKh)
    softmax_kernel<<<dim3(16384), blk256, 0, stream>>>(s, p);

    // wv -> bf16, then V^T = (x @ wv^T)^T directly (1-term, transposed store)
    cvt_kernel<<<dim3(512), blk256, 0, stream>>>(wv, wvh, DD);
    mfma_gemm256<1, 3><<<dim3(64, 4, 1), blk512, 0, stream>>>(
        xh, nullptr, 0, D, wvh, nullptr, 0, D,
        nullptr, Vt, nullptr, 0, 0, D, nullptr, 0);

    // out = p @ V = p @ (V^T)^T  (1-term BK=64, NT form, f32 out)
    mfma_gemm256<1, 0><<<dim3(8, 4, 8), blk512, 0, stream>>>(
        p, nullptr, SS, S, Vt, nullptr, SD, S,
        out, nullptr, nullptr, SD, D, S, nullptr, 0);
}